// Round 5
// baseline (149.523 us; speedup 1.0000x reference)
//
#include <hip/hip_runtime.h>
#include <cstddef>

#define HQ 2048
#define NKVH 4
#define HDIM 128
#define QKV_N 3072
#define ATT_SCALE 0.08838834764831845f
#define KSPLIT 16
#define CHUNK 128
#define NCH 32

__device__ __forceinline__ float4 f4max(float4 a, float4 b) {
  return make_float4(fmaxf(a.x, b.x), fmaxf(a.y, b.y), fmaxf(a.z, b.z), fmaxf(a.w, b.w));
}

// ---------------------------------------------------------------------------
// Projection: part[ksb][32][N] = X[32][2048] @ W[k-slice][N], K-split 16x128.
// grid (N/128, 16), block 256 = 64 lanes x 4 ksub; 2 cols per thread.
// ---------------------------------------------------------------------------
template <int N>
__global__ __launch_bounds__(256) void proj_kernel(const float* __restrict__ X,
                                                   const float* __restrict__ W,
                                                   float* __restrict__ part) {
  __shared__ union {
    float x[32][128];
    float red[32][4][64];
  } sm;
  const int t = threadIdx.x;
  const int c0 = blockIdx.x << 7;  // 128 cols per block
  const int ksb = blockIdx.y;
  const int k0 = ksb << 7;
  const int c = t & 63;
  const int ksub = t >> 6;

#pragma unroll
  for (int i = 0; i < 4; ++i) {
    const int id = t + (i << 8);
    const int bb = id >> 5, kk = (id & 31) << 2;
    *reinterpret_cast<float4*>(&sm.x[bb][kk]) =
        *reinterpret_cast<const float4*>(X + bb * HQ + k0 + kk);
  }
  __syncthreads();

  float acc0[32], acc1[32];
#pragma unroll
  for (int b = 0; b < 32; ++b) { acc0[b] = 0.f; acc1[b] = 0.f; }

#pragma unroll
  for (int kk4 = 0; kk4 < 8; ++kk4) {
    const int kk = (ksub << 5) + (kk4 << 2);
    const float* wp = W + (size_t)(k0 + kk) * N + c0 + c;
    const float w0a = wp[0],     w0b = wp[64];
    const float w1a = wp[N],     w1b = wp[N + 64];
    const float w2a = wp[2 * N], w2b = wp[2 * N + 64];
    const float w3a = wp[3 * N], w3b = wp[3 * N + 64];
#pragma unroll
    for (int b = 0; b < 32; ++b) {
      const float4 x4 = *reinterpret_cast<const float4*>(&sm.x[b][kk]);
      acc0[b] = fmaf(x4.x, w0a, acc0[b]);
      acc0[b] = fmaf(x4.y, w1a, acc0[b]);
      acc0[b] = fmaf(x4.z, w2a, acc0[b]);
      acc0[b] = fmaf(x4.w, w3a, acc0[b]);
      acc1[b] = fmaf(x4.x, w0b, acc1[b]);
      acc1[b] = fmaf(x4.y, w1b, acc1[b]);
      acc1[b] = fmaf(x4.z, w2b, acc1[b]);
      acc1[b] = fmaf(x4.w, w3b, acc1[b]);
    }
  }

  // reduce ksub for col-half 0
  __syncthreads();
#pragma unroll
  for (int b = 0; b < 32; ++b) sm.red[b][ksub][c] = acc0[b];
  __syncthreads();
#pragma unroll
  for (int i = 0; i < 8; ++i) {
    const int o = t + (i << 8);
    const int b = o >> 6, cc = o & 63;
    const float v = sm.red[b][0][cc] + sm.red[b][1][cc] + sm.red[b][2][cc] + sm.red[b][3][cc];
    part[(size_t)(ksb * 32 + b) * N + c0 + cc] = v;
  }
  // reduce ksub for col-half 1
  __syncthreads();
#pragma unroll
  for (int b = 0; b < 32; ++b) sm.red[b][ksub][c] = acc1[b];
  __syncthreads();
#pragma unroll
  for (int i = 0; i < 8; ++i) {
    const int o = t + (i << 8);
    const int b = o >> 6, cc = o & 63;
    const float v = sm.red[b][0][cc] + sm.red[b][1][cc] + sm.red[b][2][cc] + sm.red[b][3][cc];
    part[(size_t)(ksb * 32 + b) * N + c0 + 64 + cc] = v;
  }
}

template <int NCOL, bool HAS_BIAS>
__global__ __launch_bounds__(256) void reduce_kernel(const float* __restrict__ part,
                                                     const float* __restrict__ bias,
                                                     float* __restrict__ out) {
  const int o = blockIdx.x * 256 + threadIdx.x;
  constexpr int total = 32 * NCOL;
  float s = 0.f;
#pragma unroll
  for (int ks = 0; ks < KSPLIT; ++ks) s += part[(size_t)ks * total + o];
  if (HAS_BIAS) s += bias[o % NCOL];
  out[o] = s;
}

// ---------------------------------------------------------------------------
// Pass S: raw scores. grid 4096 (b,kvh,chunk), block 256, wave = 32 rows.
// Zero LDS, zero barriers: pure K streaming.
// scores[bid][128][4], wmax[bid][4 waves][4 heads].
// ---------------------------------------------------------------------------
__global__ __launch_bounds__(256, 3) void score_kernel(const float* __restrict__ cache,
                                                       const int* __restrict__ seq_lens,
                                                       const int* __restrict__ slot_map,
                                                       const float* __restrict__ qkv,
                                                       float* __restrict__ scores,
                                                       float* __restrict__ wmax) {
  const int t = threadIdx.x;
  const int bid = blockIdx.x;
  const int chunk = bid & 31;
  const int kvh = (bid >> 5) & 3;
  const int b = bid >> 7;
  const int L = seq_lens[b];
  const int start = chunk << 7;
  if (start >= L) return;
  const int n = min(CHUNK, L - start);
  const int send = start + n;
  const int slot = slot_map[b];
  const float* __restrict__ qrow = qkv + b * QKV_N;
  const float* __restrict__ knew = qrow + 2048 + (kvh << 7);

  const int w = t >> 6, l = t & 63;
  const int l16 = l & 15, rq = l >> 4;
  const int wbase = w << 5;

  float4 qr[4][2];
#pragma unroll
  for (int g = 0; g < 4; ++g) {
#pragma unroll
    for (int e = 0; e < 2; ++e)
      qr[g][e] = *reinterpret_cast<const float4*>(qrow + ((kvh << 2) + g) * HDIM +
                                                  (l16 << 3) + (e << 2));
  }

  auto krow_ptr = [&](int r) -> const float* {
    int sg = start + r;
    sg = (sg < send) ? sg : start;  // clamp; garbage rows masked in P
    return (sg == slot) ? knew : cache + (((size_t)((b << 12) + sg)) << 10) + (kvh << 7);
  };
  auto kload = [&](int st, float4* dst) {
#pragma unroll
    for (int rg = 0; rg < 4; ++rg) {
      const float* kp = krow_ptr(wbase + (st << 4) + (rg << 2) + rq) + (l16 << 3);
      dst[2 * rg] = *reinterpret_cast<const float4*>(kp);
      dst[2 * rg + 1] = *reinterpret_cast<const float4*>(kp + 4);
    }
  };

  float4 ka[8], kb[8];
  kload(0, ka);
  kload(1, kb);

  float4 m4 = make_float4(-1e30f, -1e30f, -1e30f, -1e30f);
  auto score_st = [&](int st, const float4* kr) {
#pragma unroll
    for (int rg = 0; rg < 4; ++rg) {
      const float4 k0 = kr[2 * rg], k1 = kr[2 * rg + 1];
      float s0 = fmaf(k0.x, qr[0][0].x, fmaf(k0.y, qr[0][0].y, fmaf(k0.z, qr[0][0].z, k0.w * qr[0][0].w)));
      s0 = fmaf(k1.x, qr[0][1].x, fmaf(k1.y, qr[0][1].y, fmaf(k1.z, qr[0][1].z, fmaf(k1.w, qr[0][1].w, s0))));
      float s1 = fmaf(k0.x, qr[1][0].x, fmaf(k0.y, qr[1][0].y, fmaf(k0.z, qr[1][0].z, k0.w * qr[1][0].w)));
      s1 = fmaf(k1.x, qr[1][1].x, fmaf(k1.y, qr[1][1].y, fmaf(k1.z, qr[1][1].z, fmaf(k1.w, qr[1][1].w, s1))));
      float s2 = fmaf(k0.x, qr[2][0].x, fmaf(k0.y, qr[2][0].y, fmaf(k0.z, qr[2][0].z, k0.w * qr[2][0].w)));
      s2 = fmaf(k1.x, qr[2][1].x, fmaf(k1.y, qr[2][1].y, fmaf(k1.z, qr[2][1].z, fmaf(k1.w, qr[2][1].w, s2))));
      float s3 = fmaf(k0.x, qr[3][0].x, fmaf(k0.y, qr[3][0].y, fmaf(k0.z, qr[3][0].z, k0.w * qr[3][0].w)));
      s3 = fmaf(k1.x, qr[3][1].x, fmaf(k1.y, qr[3][1].y, fmaf(k1.z, qr[3][1].z, fmaf(k1.w, qr[3][1].w, s3))));
#pragma unroll
      for (int off = 1; off <= 8; off <<= 1) {
        s0 += __shfl_xor(s0, off);
        s1 += __shfl_xor(s1, off);
        s2 += __shfl_xor(s2, off);
        s3 += __shfl_xor(s3, off);
      }
      const int row = wbase + (st << 4) + (rg << 2) + rq;
      const float4 sc = make_float4(s0 * ATT_SCALE, s1 * ATT_SCALE, s2 * ATT_SCALE, s3 * ATT_SCALE);
      if (row < n) m4 = f4max(m4, sc);
      if (l16 == 0)
        *reinterpret_cast<float4*>(scores + ((size_t)bid << 9) + (row << 2)) = sc;
    }
  };

  score_st(0, ka);
  score_st(1, kb);

  m4.x = fmaxf(m4.x, __shfl_xor(m4.x, 16));
  m4.y = fmaxf(m4.y, __shfl_xor(m4.y, 16));
  m4.z = fmaxf(m4.z, __shfl_xor(m4.z, 16));
  m4.w = fmaxf(m4.w, __shfl_xor(m4.w, 16));
  m4.x = fmaxf(m4.x, __shfl_xor(m4.x, 32));
  m4.y = fmaxf(m4.y, __shfl_xor(m4.y, 32));
  m4.z = fmaxf(m4.z, __shfl_xor(m4.z, 32));
  m4.w = fmaxf(m4.w, __shfl_xor(m4.w, 32));
  if (l == 0) *reinterpret_cast<float4*>(wmax + (bid << 4) + (w << 2)) = m4;
}

// ---------------------------------------------------------------------------
// Pass P: probs + PV. grid 4096, block 256, wave = 32 rows. One barrier total.
// ---------------------------------------------------------------------------
__global__ __launch_bounds__(256, 3) void pv_kernel(const float* __restrict__ cache,
                                                    const int* __restrict__ seq_lens,
                                                    const int* __restrict__ slot_map,
                                                    const float* __restrict__ qkv,
                                                    const float* __restrict__ scores,
                                                    const float* __restrict__ wmax,
                                                    float* __restrict__ ml,
                                                    float* __restrict__ accp) {
  __shared__ float pt[4][32][4];
  __shared__ float pvbuf[4][128][4];
  __shared__ float redl[4][4];

  const int t = threadIdx.x;
  const int bid = blockIdx.x;
  const int chunk = bid & 31;
  const int kvh = (bid >> 5) & 3;
  const int b = bid >> 7;
  const int L = seq_lens[b];
  const int start = chunk << 7;
  if (start >= L) return;
  const int n = min(CHUNK, L - start);
  const int send = start + n;
  const int slot = slot_map[b];
  const float* __restrict__ vnew = qkv + b * QKV_N + 2560 + (kvh << 7);

  const int w = t >> 6, l = t & 63;
  const int wbase = w << 5;

  auto vrow_ptr = [&](int r) -> const float* {
    int sg = start + r;
    sg = (sg < send) ? sg : start;
    return (sg == slot) ? vnew : cache + (((size_t)((b << 12) + sg)) << 10) + 512 + (kvh << 7);
  };
  auto vload = [&](int vt, float2* dst) {
#pragma unroll
    for (int s = 0; s < 16; ++s)
      dst[s] = *reinterpret_cast<const float2*>(vrow_ptr(wbase + (vt << 4) + s) + (l << 1));
  };

  // issue loads in consumption order: wmax -> scores -> va -> vb
  const float4 wm0 = *reinterpret_cast<const float4*>(wmax + (bid << 4));
  const float4 wm1 = *reinterpret_cast<const float4*>(wmax + (bid << 4) + 4);
  const float4 wm2 = *reinterpret_cast<const float4*>(wmax + (bid << 4) + 8);
  const float4 wm3 = *reinterpret_cast<const float4*>(wmax + (bid << 4) + 12);
  float4 s4 = make_float4(0.f, 0.f, 0.f, 0.f);
  if (l < 32)
    s4 = *reinterpret_cast<const float4*>(scores + ((size_t)bid << 9) + ((wbase + l) << 2));
  float2 va[16], vb[16];
  vload(0, va);
  vload(1, vb);

  const float4 M4 = f4max(f4max(wm0, wm1), f4max(wm2, wm3));
  float4 e = make_float4(0.f, 0.f, 0.f, 0.f);
  if (l < 32 && wbase + l < n) {
    e.x = __expf(s4.x - M4.x);
    e.y = __expf(s4.y - M4.y);
    e.z = __expf(s4.z - M4.z);
    e.w = __expf(s4.w - M4.w);
  }
  if (l < 32) *reinterpret_cast<float4*>(&pt[w][l][0]) = e;
  float4 l4 = e;
#pragma unroll
  for (int off = 1; off <= 32; off <<= 1) {
    l4.x += __shfl_xor(l4.x, off);
    l4.y += __shfl_xor(l4.y, off);
    l4.z += __shfl_xor(l4.z, off);
    l4.w += __shfl_xor(l4.w, off);
  }
  if (l == 0) *reinterpret_cast<float4*>(&redl[w][0]) = l4;
  asm volatile("s_waitcnt lgkmcnt(0)" ::: "memory");  // wave-private pt write->read

  float4 accA = make_float4(0.f, 0.f, 0.f, 0.f);
  float4 accB = make_float4(0.f, 0.f, 0.f, 0.f);
#pragma unroll
  for (int s = 0; s < 16; ++s) {
    const float4 p = *reinterpret_cast<const float4*>(&pt[w][s][0]);
    const float2 vv = va[s];
    accA.x = fmaf(p.x, vv.x, accA.x); accA.y = fmaf(p.y, vv.x, accA.y);
    accA.z = fmaf(p.z, vv.x, accA.z); accA.w = fmaf(p.w, vv.x, accA.w);
    accB.x = fmaf(p.x, vv.y, accB.x); accB.y = fmaf(p.y, vv.y, accB.y);
    accB.z = fmaf(p.z, vv.y, accB.z); accB.w = fmaf(p.w, vv.y, accB.w);
  }
#pragma unroll
  for (int s = 0; s < 16; ++s) {
    const float4 p = *reinterpret_cast<const float4*>(&pt[w][16 + s][0]);
    const float2 vv = vb[s];
    accA.x = fmaf(p.x, vv.x, accA.x); accA.y = fmaf(p.y, vv.x, accA.y);
    accA.z = fmaf(p.z, vv.x, accA.z); accA.w = fmaf(p.w, vv.x, accA.w);
    accB.x = fmaf(p.x, vv.y, accB.x); accB.y = fmaf(p.y, vv.y, accB.y);
    accB.z = fmaf(p.z, vv.y, accB.z); accB.w = fmaf(p.w, vv.y, accB.w);
  }

  *reinterpret_cast<float4*>(&pvbuf[w][l << 1][0]) = accA;
  *reinterpret_cast<float4*>(&pvbuf[w][(l << 1) + 1][0]) = accB;
  __syncthreads();  // the only block barrier

  if (t < 128) {
    const int d = t;
    float4 s0 = *reinterpret_cast<const float4*>(&pvbuf[0][d][0]);
    const float4 s1 = *reinterpret_cast<const float4*>(&pvbuf[1][d][0]);
    const float4 s2 = *reinterpret_cast<const float4*>(&pvbuf[2][d][0]);
    const float4 s3 = *reinterpret_cast<const float4*>(&pvbuf[3][d][0]);
    s0.x += s1.x + s2.x + s3.x;
    s0.y += s1.y + s2.y + s3.y;
    s0.z += s1.z + s2.z + s3.z;
    s0.w += s1.w + s2.w + s3.w;
    float* ap = accp + (size_t)bid * 512;
    ap[d] = s0.x;
    ap[128 + d] = s0.y;
    ap[256 + d] = s0.z;
    ap[384 + d] = s0.w;
  }
  if (t == 0) {
    float4 Lt = *reinterpret_cast<const float4*>(&redl[0][0]);
    const float4 l1 = *reinterpret_cast<const float4*>(&redl[1][0]);
    const float4 l2 = *reinterpret_cast<const float4*>(&redl[2][0]);
    const float4 l3 = *reinterpret_cast<const float4*>(&redl[3][0]);
    Lt.x += l1.x + l2.x + l3.x;
    Lt.y += l1.y + l2.y + l3.y;
    Lt.z += l1.z + l2.z + l3.z;
    Lt.w += l1.w + l2.w + l3.w;
    *reinterpret_cast<float4*>(ml + (size_t)bid * 8) = M4;
    *reinterpret_cast<float4*>(ml + (size_t)bid * 8 + 4) = Lt;
  }
}

// ---------------------------------------------------------------------------
// Combine chunk partials. grid 512 = (b,kvh,g), block 128 (d).
// ---------------------------------------------------------------------------
__global__ __launch_bounds__(128) void combine_kernel(const int* __restrict__ seq_lens,
                                                      const float* __restrict__ ml,
                                                      const float* __restrict__ accp,
                                                      float* __restrict__ attn) {
  const int blk = blockIdx.x;
  const int g = blk & 3, kvh = (blk >> 2) & 3, b = blk >> 4;
  const int d = threadIdx.x;
  const int L = seq_lens[b];
  const int nch = (L + CHUNK - 1) >> 7;
  const int base = (b * 4 + kvh) * NCH;

  float M = -1e30f;
  for (int c = 0; c < nch; ++c) M = fmaxf(M, ml[(size_t)(base + c) * 8 + g]);
  float osum = 0.f, lsum = 0.f;
  for (int c = 0; c < nch; ++c) {
    const int idx = base + c;
    const float mc = ml[(size_t)idx * 8 + g];
    const float lc = ml[(size_t)idx * 8 + 4 + g];
    const float wgt = __expf(mc - M);
    lsum = fmaf(lc, wgt, lsum);
    osum = fmaf(wgt, accp[(size_t)idx * 512 + g * 128 + d], osum);
  }
  attn[(size_t)b * HQ + kvh * 512 + g * 128 + d] = osum / lsum;
}

// ---------------------------------------------------------------------------
extern "C" void kernel_launch(void* const* d_in, const int* in_sizes, int n_in,
                              void* d_out, int out_size, void* d_ws, size_t ws_size,
                              hipStream_t stream) {
  const float* hidden = (const float*)d_in[0];
  const float* cache = (const float*)d_in[2];
  const int* slot_map = (const int*)d_in[3];
  const int* seq_lens = (const int*)d_in[4];
  const float* Wqkv = (const float*)d_in[5];
  const float* bqkv = (const float*)d_in[6];
  const float* Wo = (const float*)d_in[7];
  float* out = (float*)d_out;
  float* ws = (float*)d_ws;

  float* qkv_part = ws;            // 16*32*3072 = 1,572,864
  float* qkv      = ws + 1572864;  // 98,304
  float* ml       = ws + 1671168;  // 4096*8 = 32,768
  float* accp     = ws + 1703936;  // 4096*512 = 2,097,152
  float* attn     = ws + 3801088;  // 65,536
  float* o_part   = ws + 3866624;  // 16*32*2048 = 1,048,576
  float* scores   = ws + 4915200;  // 4096*512 = 2,097,152
  float* wmax     = ws + 7012352;  // 4096*16 = 65,536

  proj_kernel<QKV_N><<<dim3(24, KSPLIT), 256, 0, stream>>>(hidden, Wqkv, qkv_part);
  reduce_kernel<QKV_N, true><<<384, 256, 0, stream>>>(qkv_part, bqkv, qkv);
  score_kernel<<<4096, 256, 0, stream>>>(cache, seq_lens, slot_map, qkv, scores, wmax);
  pv_kernel<<<4096, 256, 0, stream>>>(cache, seq_lens, slot_map, qkv, scores, wmax, ml, accp);
  combine_kernel<<<512, 128, 0, stream>>>(seq_lens, ml, accp, attn);
  proj_kernel<HQ><<<dim3(16, KSPLIT), 256, 0, stream>>>(attn, Wo, o_part);
  reduce_kernel<HQ, false><<<256, 256, 0, stream>>>(o_part, nullptr, out);
}

// Round 6
// 132.585 us; speedup vs baseline: 1.1277x; 1.1277x over previous
//
#include <hip/hip_runtime.h>
#include <cstddef>

#define HQ 2048
#define NKVH 4
#define HDIM 128
#define QKV_N 3072
#define ATT_SCALE 0.08838834764831845f
#define KSPLIT 16
#define CHUNK 64
#define NCH 64

__device__ __forceinline__ float4 f4max(float4 a, float4 b) {
  return make_float4(fmaxf(a.x, b.x), fmaxf(a.y, b.y), fmaxf(a.z, b.z), fmaxf(a.w, b.w));
}

// ---------------------------------------------------------------------------
// Projection: part[ksb][32][N] = X[32][2048] @ W[k-slice][N], K-split 16x128.
// grid (N/64, 16), block 256 = 64 cols x 4 ksub (32 K each).  [unchanged, R3]
// ---------------------------------------------------------------------------
template <int N>
__global__ __launch_bounds__(256) void proj_kernel(const float* __restrict__ X,
                                                   const float* __restrict__ W,
                                                   float* __restrict__ part) {
  __shared__ union {
    float x[32][128];
    float red[32][4][64];
  } sm;
  const int t = threadIdx.x;
  const int c0 = blockIdx.x << 6;
  const int ksb = blockIdx.y;
  const int k0 = ksb << 7;
  const int c = t & 63;
  const int ksub = t >> 6;

#pragma unroll
  for (int i = 0; i < 4; ++i) {
    const int id = t + (i << 8);
    const int bb = id >> 5, kk = (id & 31) << 2;
    *reinterpret_cast<float4*>(&sm.x[bb][kk]) =
        *reinterpret_cast<const float4*>(X + bb * HQ + k0 + kk);
  }
  __syncthreads();

  float acc[32];
#pragma unroll
  for (int b = 0; b < 32; ++b) acc[b] = 0.f;

#pragma unroll
  for (int kk4 = 0; kk4 < 8; ++kk4) {
    const int kk = (ksub << 5) + (kk4 << 2);
    const float* wp = W + (size_t)(k0 + kk) * N + c0 + c;
    const float w0 = wp[0];
    const float w1 = wp[N];
    const float w2 = wp[2 * N];
    const float w3 = wp[3 * N];
#pragma unroll
    for (int b = 0; b < 32; ++b) {
      const float4 x4 = *reinterpret_cast<const float4*>(&sm.x[b][kk]);
      acc[b] = fmaf(x4.x, w0, acc[b]);
      acc[b] = fmaf(x4.y, w1, acc[b]);
      acc[b] = fmaf(x4.z, w2, acc[b]);
      acc[b] = fmaf(x4.w, w3, acc[b]);
    }
  }
  __syncthreads();
#pragma unroll
  for (int b = 0; b < 32; ++b) sm.red[b][ksub][c] = acc[b];
  __syncthreads();
#pragma unroll
  for (int i = 0; i < 8; ++i) {
    const int o = t + (i << 8);
    const int b = o >> 6, cc = o & 63;
    const float v = sm.red[b][0][cc] + sm.red[b][1][cc] + sm.red[b][2][cc] + sm.red[b][3][cc];
    part[(size_t)(ksb * 32 + b) * N + c0 + cc] = v;
  }
}

template <int NCOL, bool HAS_BIAS>
__global__ __launch_bounds__(256) void reduce_kernel(const float* __restrict__ part,
                                                     const float* __restrict__ bias,
                                                     float* __restrict__ out) {
  const int o = blockIdx.x * 256 + threadIdx.x;
  constexpr int total = 32 * NCOL;
  float s = 0.f;
#pragma unroll
  for (int ks = 0; ks < KSPLIT; ++ks) s += part[(size_t)ks * total + o];
  if (HAS_BIAS) s += bias[o % NCOL];
  out[o] = s;
}

// ---------------------------------------------------------------------------
// Flash-decode attention, CHUNK=64, 16 rows/wave, ~120 VGPR -> 4 waves/SIMD.
// grid 32*4*64 = 8192, block 256. All loads issued up front; V lands before
// the single mid-kernel barrier; PV runs from regs + wave-private LDS probs.
// ---------------------------------------------------------------------------
__global__ __launch_bounds__(256, 4) void attn_kernel(const float* __restrict__ cache,
                                                      const int* __restrict__ seq_lens,
                                                      const int* __restrict__ slot_map,
                                                      const float* __restrict__ qkv,
                                                      float* __restrict__ ml,
                                                      float* __restrict__ accp) {
  __shared__ float pt[4][16][4];
  __shared__ float pvbuf[4][128][4];
  __shared__ float redm[4][4];
  __shared__ float redl[4][4];

  const int t = threadIdx.x;
  const int bid = blockIdx.x;
  const int chunk = bid & 63;
  const int kvh = (bid >> 6) & 3;
  const int b = bid >> 8;
  const int L = seq_lens[b];
  const int start = chunk << 6;
  if (start >= L) return;
  const int n = min(CHUNK, L - start);
  const int send = start + n;
  const int slot = slot_map[b];
  const float* __restrict__ qrow = qkv + b * QKV_N;
  const float* __restrict__ knew = qrow + 2048 + (kvh << 7);
  const float* __restrict__ vnew = qrow + 2560 + (kvh << 7);

  const int w = t >> 6, l = t & 63;
  const int l16 = l & 15, rq = l >> 4;
  const int wbase = w << 4;  // 16 rows per wave

  auto krow_ptr = [&](int r) -> const float* {
    int sg = start + r;
    sg = (sg < send) ? sg : start;  // clamp; garbage rows masked later
    return (sg == slot) ? knew : cache + (((size_t)((b << 12) + sg)) << 10) + (kvh << 7);
  };
  auto vrow_ptr = [&](int r) -> const float* {
    int sg = start + r;
    sg = (sg < send) ? sg : start;
    return (sg == slot) ? vnew : cache + (((size_t)((b << 12) + sg)) << 10) + 512 + (kvh << 7);
  };

  // ---- issue all loads up front: q, K(16 rows), V(16 rows) ----
  float4 qr[4][2];
#pragma unroll
  for (int g = 0; g < 4; ++g) {
#pragma unroll
    for (int e = 0; e < 2; ++e)
      qr[g][e] = *reinterpret_cast<const float4*>(qrow + ((kvh << 2) + g) * HDIM +
                                                  (l16 << 3) + (e << 2));
  }
  float4 ka[8];
#pragma unroll
  for (int rg = 0; rg < 4; ++rg) {
    const float* kp = krow_ptr(wbase + (rg << 2) + rq) + (l16 << 3);
    ka[2 * rg] = *reinterpret_cast<const float4*>(kp);
    ka[2 * rg + 1] = *reinterpret_cast<const float4*>(kp + 4);
  }
  float2 va[16];
#pragma unroll
  for (int s = 0; s < 16; ++s)
    va[s] = *reinterpret_cast<const float2*>(vrow_ptr(wbase + s) + (l << 1));

  // ---- scores: 16 lanes per row, shfl-reduce over dim groups ----
  float4 m4 = make_float4(-1e30f, -1e30f, -1e30f, -1e30f);
  float4 scr[4];
#pragma unroll
  for (int rg = 0; rg < 4; ++rg) {
    const float4 k0 = ka[2 * rg], k1 = ka[2 * rg + 1];
    float s0 = fmaf(k0.x, qr[0][0].x, fmaf(k0.y, qr[0][0].y, fmaf(k0.z, qr[0][0].z, k0.w * qr[0][0].w)));
    s0 = fmaf(k1.x, qr[0][1].x, fmaf(k1.y, qr[0][1].y, fmaf(k1.z, qr[0][1].z, fmaf(k1.w, qr[0][1].w, s0))));
    float s1 = fmaf(k0.x, qr[1][0].x, fmaf(k0.y, qr[1][0].y, fmaf(k0.z, qr[1][0].z, k0.w * qr[1][0].w)));
    s1 = fmaf(k1.x, qr[1][1].x, fmaf(k1.y, qr[1][1].y, fmaf(k1.z, qr[1][1].z, fmaf(k1.w, qr[1][1].w, s1))));
    float s2 = fmaf(k0.x, qr[2][0].x, fmaf(k0.y, qr[2][0].y, fmaf(k0.z, qr[2][0].z, k0.w * qr[2][0].w)));
    s2 = fmaf(k1.x, qr[2][1].x, fmaf(k1.y, qr[2][1].y, fmaf(k1.z, qr[2][1].z, fmaf(k1.w, qr[2][1].w, s2))));
    float s3 = fmaf(k0.x, qr[3][0].x, fmaf(k0.y, qr[3][0].y, fmaf(k0.z, qr[3][0].z, k0.w * qr[3][0].w)));
    s3 = fmaf(k1.x, qr[3][1].x, fmaf(k1.y, qr[3][1].y, fmaf(k1.z, qr[3][1].z, fmaf(k1.w, qr[3][1].w, s3))));
#pragma unroll
    for (int off = 1; off <= 8; off <<= 1) {
      s0 += __shfl_xor(s0, off);
      s1 += __shfl_xor(s1, off);
      s2 += __shfl_xor(s2, off);
      s3 += __shfl_xor(s3, off);
    }
    scr[rg] = make_float4(s0 * ATT_SCALE, s1 * ATT_SCALE, s2 * ATT_SCALE, s3 * ATT_SCALE);
    if (wbase + (rg << 2) + rq < n) m4 = f4max(m4, scr[rg]);
  }

  // wave max over row slots (bits 4,5)
  m4.x = fmaxf(m4.x, __shfl_xor(m4.x, 16));
  m4.y = fmaxf(m4.y, __shfl_xor(m4.y, 16));
  m4.z = fmaxf(m4.z, __shfl_xor(m4.z, 16));
  m4.w = fmaxf(m4.w, __shfl_xor(m4.w, 16));
  m4.x = fmaxf(m4.x, __shfl_xor(m4.x, 32));
  m4.y = fmaxf(m4.y, __shfl_xor(m4.y, 32));
  m4.z = fmaxf(m4.z, __shfl_xor(m4.z, 32));
  m4.w = fmaxf(m4.w, __shfl_xor(m4.w, 32));
  if (l == 0) *reinterpret_cast<float4*>(&redm[w][0]) = m4;
  __syncthreads();  // barrier A (V loads have landed by now)
  float4 M4 = *reinterpret_cast<const float4*>(&redm[0][0]);
  M4 = f4max(M4, *reinterpret_cast<const float4*>(&redm[1][0]));
  M4 = f4max(M4, *reinterpret_cast<const float4*>(&redm[2][0]));
  M4 = f4max(M4, *reinterpret_cast<const float4*>(&redm[3][0]));

  // probs (replicated over l16) -> wave-private LDS; running sum
  float4 lsum = make_float4(0.f, 0.f, 0.f, 0.f);
#pragma unroll
  for (int rg = 0; rg < 4; ++rg) {
    const int row = wbase + (rg << 2) + rq;
    float4 e = make_float4(0.f, 0.f, 0.f, 0.f);
    if (row < n) {
      e.x = __expf(scr[rg].x - M4.x);
      e.y = __expf(scr[rg].y - M4.y);
      e.z = __expf(scr[rg].z - M4.z);
      e.w = __expf(scr[rg].w - M4.w);
    }
    lsum.x += e.x; lsum.y += e.y; lsum.z += e.z; lsum.w += e.w;
    if (l16 == 0) *reinterpret_cast<float4*>(&pt[w][(rg << 2) + rq][0]) = e;
  }
  // sum over row slots only (lanes within a slot hold identical values)
  lsum.x += __shfl_xor(lsum.x, 16); lsum.y += __shfl_xor(lsum.y, 16);
  lsum.z += __shfl_xor(lsum.z, 16); lsum.w += __shfl_xor(lsum.w, 16);
  lsum.x += __shfl_xor(lsum.x, 32); lsum.y += __shfl_xor(lsum.y, 32);
  lsum.z += __shfl_xor(lsum.z, 32); lsum.w += __shfl_xor(lsum.w, 32);
  if (l == 0) *reinterpret_cast<float4*>(&redl[w][0]) = lsum;
  asm volatile("s_waitcnt lgkmcnt(0)" ::: "memory");  // wave-private pt fence

  // PV: lane covers dims 2l, 2l+1 for 4 heads
  float4 accA = make_float4(0.f, 0.f, 0.f, 0.f);
  float4 accB = make_float4(0.f, 0.f, 0.f, 0.f);
#pragma unroll
  for (int s = 0; s < 16; ++s) {
    const float4 p = *reinterpret_cast<const float4*>(&pt[w][s][0]);
    const float2 vv = va[s];
    accA.x = fmaf(p.x, vv.x, accA.x); accA.y = fmaf(p.y, vv.x, accA.y);
    accA.z = fmaf(p.z, vv.x, accA.z); accA.w = fmaf(p.w, vv.x, accA.w);
    accB.x = fmaf(p.x, vv.y, accB.x); accB.y = fmaf(p.y, vv.y, accB.y);
    accB.z = fmaf(p.z, vv.y, accB.z); accB.w = fmaf(p.w, vv.y, accB.w);
  }

  *reinterpret_cast<float4*>(&pvbuf[w][l << 1][0]) = accA;
  *reinterpret_cast<float4*>(&pvbuf[w][(l << 1) + 1][0]) = accB;
  __syncthreads();  // barrier B

  if (t < 128) {
    const int d = t;
    float4 s0 = *reinterpret_cast<const float4*>(&pvbuf[0][d][0]);
    const float4 s1 = *reinterpret_cast<const float4*>(&pvbuf[1][d][0]);
    const float4 s2 = *reinterpret_cast<const float4*>(&pvbuf[2][d][0]);
    const float4 s3 = *reinterpret_cast<const float4*>(&pvbuf[3][d][0]);
    s0.x += s1.x + s2.x + s3.x;
    s0.y += s1.y + s2.y + s3.y;
    s0.z += s1.z + s2.z + s3.z;
    s0.w += s1.w + s2.w + s3.w;
    float* ap = accp + (size_t)bid * 512;
    ap[d] = s0.x;
    ap[128 + d] = s0.y;
    ap[256 + d] = s0.z;
    ap[384 + d] = s0.w;
  }
  if (t == 0) {
    float4 Lt = *reinterpret_cast<const float4*>(&redl[0][0]);
    const float4 l1 = *reinterpret_cast<const float4*>(&redl[1][0]);
    const float4 l2 = *reinterpret_cast<const float4*>(&redl[2][0]);
    const float4 l3 = *reinterpret_cast<const float4*>(&redl[3][0]);
    Lt.x += l1.x + l2.x + l3.x;
    Lt.y += l1.y + l2.y + l3.y;
    Lt.z += l1.z + l2.z + l3.z;
    Lt.w += l1.w + l2.w + l3.w;
    *reinterpret_cast<float4*>(ml + (size_t)bid * 8) = M4;
    *reinterpret_cast<float4*>(ml + (size_t)bid * 8 + 4) = Lt;
  }
}

// ---------------------------------------------------------------------------
// Combine chunk partials. grid 512 = (b,kvh,g), block 128 (d).
// ---------------------------------------------------------------------------
__global__ __launch_bounds__(128) void combine_kernel(const int* __restrict__ seq_lens,
                                                      const float* __restrict__ ml,
                                                      const float* __restrict__ accp,
                                                      float* __restrict__ attn) {
  const int blk = blockIdx.x;
  const int g = blk & 3, kvh = (blk >> 2) & 3, b = blk >> 4;
  const int d = threadIdx.x;
  const int L = seq_lens[b];
  const int nch = (L + CHUNK - 1) >> 6;
  const int base = (b * 4 + kvh) * NCH;

  float M = -1e30f;
  for (int c = 0; c < nch; ++c) M = fmaxf(M, ml[(size_t)(base + c) * 8 + g]);
  float osum = 0.f, lsum = 0.f;
  for (int c = 0; c < nch; ++c) {
    const int idx = base + c;
    const float mc = ml[(size_t)idx * 8 + g];
    const float lc = ml[(size_t)idx * 8 + 4 + g];
    const float wgt = __expf(mc - M);
    lsum = fmaf(lc, wgt, lsum);
    osum = fmaf(wgt, accp[(size_t)idx * 512 + g * 128 + d], osum);
  }
  attn[(size_t)b * HQ + kvh * 512 + g * 128 + d] = osum / lsum;
}

// ---------------------------------------------------------------------------
extern "C" void kernel_launch(void* const* d_in, const int* in_sizes, int n_in,
                              void* d_out, int out_size, void* d_ws, size_t ws_size,
                              hipStream_t stream) {
  const float* hidden = (const float*)d_in[0];
  const float* cache = (const float*)d_in[2];
  const int* slot_map = (const int*)d_in[3];
  const int* seq_lens = (const int*)d_in[4];
  const float* Wqkv = (const float*)d_in[5];
  const float* bqkv = (const float*)d_in[6];
  const float* Wo = (const float*)d_in[7];
  float* out = (float*)d_out;
  float* ws = (float*)d_ws;

  float* qkv_part = ws;            // 16*32*3072 = 1,572,864
  float* qkv      = ws + 1572864;  // 98,304
  float* ml       = ws + 1671168;  // 8192*8 = 65,536
  float* accp     = ws + 1736704;  // 8192*512 = 4,194,304
  float* attn     = ws + 5931008;  // 65,536
  float* o_part   = ws + 5996544;  // 16*32*2048 = 1,048,576

  proj_kernel<QKV_N><<<dim3(48, KSPLIT), 256, 0, stream>>>(hidden, Wqkv, qkv_part);
  reduce_kernel<QKV_N, true><<<384, 256, 0, stream>>>(qkv_part, bqkv, qkv);
  attn_kernel<<<8192, 256, 0, stream>>>(cache, seq_lens, slot_map, qkv, ml, accp);
  combine_kernel<<<512, 128, 0, stream>>>(seq_lens, ml, accp, attn);
  proj_kernel<HQ><<<dim3(32, KSPLIT), 256, 0, stream>>>(attn, Wo, o_part);
  reduce_kernel<HQ, false><<<256, 256, 0, stream>>>(o_part, nullptr, out);
}